// Round 3
// baseline (173.736 us; speedup 1.0000x reference)
//
#include <hip/hip_runtime.h>
#include <math.h>

#define C_DIMK 2048
#define I_DIMK 4096
#define NV4    (I_DIMK / 4)   // float4 chunks per weight row (16 per lane per wave)

typedef __attribute__((address_space(1))) const void* as1_cvp;
typedef __attribute__((address_space(3))) void*       as3_vp;

static __device__ __forceinline__ void load16_to_lds(const void* gsrc, void* ldst) {
    __builtin_amdgcn_global_load_lds((as1_cvp)gsrc, (as3_vp)ldst, 16, 0, 0);
}

// One block per output row r; 4 waves, wave w owns gate w (f,i,c,o).
// All staging goes through global_load_lds (async DMA, no VGPR round-trip):
//  - xs: 16 KB cat(x,h), 4 instrs/wave
//  - wbuf[w]: 16 KB of gate-w's weight row, 16 instrs/wave (16 KB in flight/wave)
// __syncthreads() drains vmcnt; consume from LDS with ds_read_b128.
__global__ __launch_bounds__(256, 2) void lstm_fused_kernel(
    const float* __restrict__ h, const float* __restrict__ c,
    const float* __restrict__ x,
    const float* __restrict__ wf, const float* __restrict__ bf,
    const float* __restrict__ wi, const float* __restrict__ bi,
    const float* __restrict__ wo, const float* __restrict__ bo,
    const float* __restrict__ wc, const float* __restrict__ bc,
    float* __restrict__ out)
{
    __shared__ float4 wbuf[4][NV4];   // 64 KB weight staging (wave-linear layout)
    __shared__ float4 xs[NV4];        // 16 KB cat(x, h)
    __shared__ float  partial[4];

    const int r    = blockIdx.x;
    const int t    = threadIdx.x;
    const int wave = t >> 6;          // 0..3 -> gate f,i,c,o
    const int lane = t & 63;

    // Gate order matches reference g-layout: [f, i, c, o]
    const float* W = (wave == 0) ? wf : (wave == 1) ? wi : (wave == 2) ? wc : wo;
    const float4* Wrow = reinterpret_cast<const float4*>(W) + (size_t)r * NV4;
    const float4* X4 = reinterpret_cast<const float4*>(x);
    const float4* H4 = reinterpret_cast<const float4*>(h);

    // Stage cat(x,h): wave w covers float4 blocks [w*4, w*4+4) of 16 total.
    #pragma unroll
    for (int k = 0; k < 4; ++k) {
        const int blk = wave * 4 + k;                 // 0..15, wave-uniform
        const float4* src = (blk < 8) ? (X4 + blk * 64 + lane)
                                      : (H4 + (blk - 8) * 64 + lane);
        load16_to_lds(src, &xs[blk * 64]);            // dst wave-uniform + lane*16B
    }

    // Stage this wave's full weight row chunk: 16 x 1 KB = 16 KB in flight.
    #pragma unroll
    for (int j = 0; j < 16; ++j)
        load16_to_lds(Wrow + j * 64 + lane, &wbuf[wave][j * 64]);

    __syncthreads();   // drains vmcnt(0): all DMA landed

    // Consume from LDS; 4 rotating accumulators break the dependent fma chain.
    float a0 = 0.f, a1 = 0.f, a2 = 0.f, a3 = 0.f;
    #pragma unroll
    for (int j = 0; j < 16; ++j) {
        const float4 xv = xs[j * 64 + lane];
        const float4 wv = wbuf[wave][j * 64 + lane];
        float d = wv.x * xv.x;
        d = fmaf(wv.y, xv.y, d);
        d = fmaf(wv.z, xv.z, d);
        d = fmaf(wv.w, xv.w, d);
        switch (j & 3) {
            case 0: a0 += d; break;
            case 1: a1 += d; break;
            case 2: a2 += d; break;
            default: a3 += d; break;
        }
    }
    float sum = (a0 + a1) + (a2 + a3);

    // Wave64 reduction
    #pragma unroll
    for (int off = 32; off > 0; off >>= 1)
        sum += __shfl_down(sum, off, 64);

    if (lane == 0) partial[wave] = sum;
    __syncthreads();

    if (t == 0) {
        const float gf = partial[0] + bf[r];
        const float gi = partial[1] + bi[r];
        const float gc = partial[2] + bc[r];
        const float go = partial[3] + bo[r];
        const float ff = 1.0f / (1.0f + __expf(-gf));
        const float ig = 1.0f / (1.0f + __expf(-gi));
        const float cc = tanhf(gc);
        const float oo = 1.0f / (1.0f + __expf(-go));
        const float cn = fmaf(ff, c[r], ig * cc);
        const float hn = tanhf(cn) * oo;
        out[r]          = cn;   // c_new
        out[C_DIMK + r] = hn;   // h_new
    }
}

extern "C" void kernel_launch(void* const* d_in, const int* in_sizes, int n_in,
                              void* d_out, int out_size, void* d_ws, size_t ws_size,
                              hipStream_t stream) {
    // setup_inputs() order: h, c, x, wf, bf, wi, bi, wo, bo, wc, bc (all fp32)
    const float* h  = (const float*)d_in[0];
    const float* c  = (const float*)d_in[1];
    const float* x  = (const float*)d_in[2];
    const float* wf = (const float*)d_in[3];
    const float* bf = (const float*)d_in[4];
    const float* wi = (const float*)d_in[5];
    const float* bi = (const float*)d_in[6];
    const float* wo = (const float*)d_in[7];
    const float* bo = (const float*)d_in[8];
    const float* wc = (const float*)d_in[9];
    const float* bc = (const float*)d_in[10];
    float* out = (float*)d_out;

    lstm_fused_kernel<<<C_DIMK, 256, 0, stream>>>(
        h, c, x, wf, bf, wi, bi, wo, bo, wc, bc, out);
}

// Round 5
// 156.281 us; speedup vs baseline: 1.1117x; 1.1117x over previous
//
#include <hip/hip_runtime.h>
#include <math.h>

#define C_DIMK 2048

typedef float f32x4 __attribute__((ext_vector_type(4)));

// One block (256 thr, 4 waves) per output row r. Gates k=0..3 = f,i,c,o.
// Thread t covers float4-cols {j*256+t, j=0..3} of the 1024-float4 row.
// x/h live in 4 float4 registers (no per-round global x traffic).
// All 16 weight loads issue back-to-back (nontemporal) BEFORE any FMA —
// sched_barrier(0) pins the batch so the compiler can't interleave/collapse.
// No __syncthreads in the hot path; one sync before the final 4x4 combine.
__global__ __launch_bounds__(256, 4) void lstm_fused_kernel(
    const float* __restrict__ h, const float* __restrict__ c,
    const float* __restrict__ x,
    const float* __restrict__ wf, const float* __restrict__ bf,
    const float* __restrict__ wi, const float* __restrict__ bi,
    const float* __restrict__ wo, const float* __restrict__ bo,
    const float* __restrict__ wc, const float* __restrict__ bc,
    float* __restrict__ out)
{
    const int r    = blockIdx.x;
    const int t    = threadIdx.x;
    const int wave = t >> 6;
    const int lane = t & 63;

    // cat(x,h) float4 index j*256+t: j=0,1 -> x, j=2,3 -> h
    const f32x4* X4 = reinterpret_cast<const f32x4*>(x);
    const f32x4* H4 = reinterpret_cast<const f32x4*>(h);
    f32x4 xv[4];
    xv[0] = X4[t];
    xv[1] = X4[256 + t];
    xv[2] = H4[t];
    xv[3] = H4[256 + t];

    const f32x4* W4[4];
    W4[0] = reinterpret_cast<const f32x4*>(wf) + (size_t)r * 1024;
    W4[1] = reinterpret_cast<const f32x4*>(wi) + (size_t)r * 1024;
    W4[2] = reinterpret_cast<const f32x4*>(wc) + (size_t)r * 1024;
    W4[3] = reinterpret_cast<const f32x4*>(wo) + (size_t)r * 1024;

    // 16 independent nontemporal float4 loads, all in flight at once.
    f32x4 wv0[4], wv1[4], wv2[4], wv3[4];
    #pragma unroll
    for (int j = 0; j < 4; ++j) wv0[j] = __builtin_nontemporal_load(&W4[0][j * 256 + t]);
    #pragma unroll
    for (int j = 0; j < 4; ++j) wv1[j] = __builtin_nontemporal_load(&W4[1][j * 256 + t]);
    #pragma unroll
    for (int j = 0; j < 4; ++j) wv2[j] = __builtin_nontemporal_load(&W4[2][j * 256 + t]);
    #pragma unroll
    for (int j = 0; j < 4; ++j) wv3[j] = __builtin_nontemporal_load(&W4[3][j * 256 + t]);
    __builtin_amdgcn_sched_barrier(0);

    // Consume: per gate, 4 independent j-chains then pairwise combine.
    float g[4];
    #pragma unroll
    for (int k = 0; k < 4; ++k) {
        const f32x4* wv = (k == 0) ? wv0 : (k == 1) ? wv1 : (k == 2) ? wv2 : wv3;
        float d0 = wv[0].x * xv[0].x;
        d0 = fmaf(wv[0].y, xv[0].y, d0);
        d0 = fmaf(wv[0].z, xv[0].z, d0);
        d0 = fmaf(wv[0].w, xv[0].w, d0);
        float d1 = wv[1].x * xv[1].x;
        d1 = fmaf(wv[1].y, xv[1].y, d1);
        d1 = fmaf(wv[1].z, xv[1].z, d1);
        d1 = fmaf(wv[1].w, xv[1].w, d1);
        float d2 = wv[2].x * xv[2].x;
        d2 = fmaf(wv[2].y, xv[2].y, d2);
        d2 = fmaf(wv[2].z, xv[2].z, d2);
        d2 = fmaf(wv[2].w, xv[2].w, d2);
        float d3 = wv[3].x * xv[3].x;
        d3 = fmaf(wv[3].y, xv[3].y, d3);
        d3 = fmaf(wv[3].z, xv[3].z, d3);
        d3 = fmaf(wv[3].w, xv[3].w, d3);
        g[k] = (d0 + d1) + (d2 + d3);
    }

    // Wave64 reductions for the 4 gate partials.
    #pragma unroll
    for (int k = 0; k < 4; ++k) {
        #pragma unroll
        for (int off = 32; off > 0; off >>= 1)
            g[k] += __shfl_down(g[k], off, 64);
    }

    __shared__ float partial[4][4];
    if (lane == 0) {
        partial[wave][0] = g[0];
        partial[wave][1] = g[1];
        partial[wave][2] = g[2];
        partial[wave][3] = g[3];
    }
    __syncthreads();

    if (t == 0) {
        const float gf = partial[0][0] + partial[1][0] + partial[2][0] + partial[3][0] + bf[r];
        const float gi = partial[0][1] + partial[1][1] + partial[2][1] + partial[3][1] + bi[r];
        const float gc = partial[0][2] + partial[1][2] + partial[2][2] + partial[3][2] + bc[r];
        const float go = partial[0][3] + partial[1][3] + partial[2][3] + partial[3][3] + bo[r];
        const float ff = 1.0f / (1.0f + __expf(-gf));
        const float ig = 1.0f / (1.0f + __expf(-gi));
        const float cc = tanhf(gc);
        const float oo = 1.0f / (1.0f + __expf(-go));
        const float cn = fmaf(ff, c[r], ig * cc);
        const float hn = tanhf(cn) * oo;
        out[r]          = cn;   // c_new
        out[C_DIMK + r] = hn;   // h_new
    }
}

extern "C" void kernel_launch(void* const* d_in, const int* in_sizes, int n_in,
                              void* d_out, int out_size, void* d_ws, size_t ws_size,
                              hipStream_t stream) {
    // setup_inputs() order: h, c, x, wf, bf, wi, bi, wo, bo, wc, bc (all fp32)
    const float* h  = (const float*)d_in[0];
    const float* c  = (const float*)d_in[1];
    const float* x  = (const float*)d_in[2];
    const float* wf = (const float*)d_in[3];
    const float* bf = (const float*)d_in[4];
    const float* wi = (const float*)d_in[5];
    const float* bi = (const float*)d_in[6];
    const float* wo = (const float*)d_in[7];
    const float* bo = (const float*)d_in[8];
    const float* wc = (const float*)d_in[9];
    const float* bc = (const float*)d_in[10];
    float* out = (float*)d_out;

    lstm_fused_kernel<<<C_DIMK, 256, 0, stream>>>(
        h, c, x, wf, bf, wi, bi, wo, bo, wc, bc, out);
}